// Round 7
// baseline (859.545 us; speedup 1.0000x reference)
//
#include <hip/hip_runtime.h>

#define NROWS    262144   // 16 * 16384
#define DIMS     64
#define KCODES   512
#define MTILE    32       // rows per tile: 4 row-groups x 8 rows
#define NTHREADS 1024     // 16 waves: 4 row-groups x 4 col-quarters
#define NBLOCKS  256      // persistent: 1 block/CU
#define NTILES   32       // row-tiles per block (256*32*32 = 262144 rows)

// Dynamic LDS layout (floats):
//   [0,512)       exchange/reduce scratch
//   [512,1024)    enorm staged copy
//   [1024,3200)   x tile, 32 rows x stride 68 (17 float4) — pad kills conflicts
//   [3200,35968)  embed as d-pair float2s: eP[dp][col] = (e[2dp][col], e[2dp+1][col])
#define XL_OFF    1024
#define XL_STRIDE 17          // float4 units per row (68 floats)
#define EP_OFF    3200
#define LDS_FLOATS (EP_OFF + DIMS * KCODES)
#define LDS_BYTES  (LDS_FLOATS * 4)

// ---------------------------------------------------------------------------
// prep: embedT[k][d] = embed[d][k]; enorm[k] = sum_d embed[d][k]^2 (numpy
// pairwise-8 order); zero the likelihood accumulator.
// ---------------------------------------------------------------------------
__global__ void prep_kernel(const float* __restrict__ embed,
                            float* __restrict__ embedT,
                            float* __restrict__ enorm,
                            float* __restrict__ lik) {
    int k = blockIdx.x;
    int d = threadIdx.x;
    float v = embed[d * KCODES + k];
    embedT[k * DIMS + d] = v;
    float sq = __fmul_rn(v, v);
    int j = d & 7;
    float r = __shfl(sq, j, 64);
#pragma unroll
    for (int i = 1; i < 8; ++i)
        r = __fadd_rn(r, __shfl(sq, j + 8 * i, 64));
    float t;
    t = __shfl_xor(r, 1, 64); r = __fadd_rn(r, t);
    t = __shfl_xor(r, 2, 64); r = __fadd_rn(r, t);
    t = __shfl_xor(r, 4, 64); r = __fadd_rn(r, t);
    if (d == 0) { enorm[k] = r; lik[k] = 0.0f; }
}

// ---------------------------------------------------------------------------
// main (persistent): 256 blocks x 1024 thr; 32 row-tiles of 32 rows each.
// Wave w: rgrp = w>>2 (8 rows), quarter = w&3 (128 cols); lane owns 2 cols
// -> acc[8][2] = 16 VGPRs. DESIGNED FOR A 44-VGPR BUDGET: the backend
// allocator has given 44-64 VGPRs across 6 rounds regardless of
// launch_bounds / waves_per_eu metadata; every acc=32 design spilled
// 0.3-1.6 GB of scratch traffic. Peak live here ~40.
// x is staged per-tile into LDS (coalesced burst, stride-68 pad) and read as
// wave-uniform LDS broadcasts — round 4/5's ~300-cy global broadcast chain
// was the latency killer. embed is stored d-pair-interleaved so each lane's
// (2 cols x 2 d) is one contiguous conflict-free ds_read_b128.
// Numerics: per-element FMA chain / z / m / ev / argmax identical to the
// passing rounds (bit-exact hard output).
// ---------------------------------------------------------------------------
__global__ void
__attribute__((amdgpu_flat_work_group_size(1024, 1024), amdgpu_waves_per_eu(4, 4)))
main_kernel(const float* __restrict__ x,
            const float* __restrict__ embed,
            const float* __restrict__ sigma,
            const float* __restrict__ embedT,
            const float* __restrict__ enorm,
            float* __restrict__ lik,
            float* __restrict__ out) {
    extern __shared__ float lds[];
    float*  scratch = lds;                                   // 512 floats
    float*  enL     = lds + 512;                             // 512 floats
    float4* xL4     = reinterpret_cast<float4*>(lds + XL_OFF);
    float4* eP4     = reinterpret_cast<float4*>(lds + EP_OFF);

    const int tid     = threadIdx.x;
    const int lane    = tid & 63;
    const int w       = tid >> 6;        // 0..15
    const int quarter = w & 3;           // col quarter (128 cols)
    const int rgrp    = w >> 2;          // row group (8 rows)
    const int colb    = quarter * 128 + 2 * lane;   // 2 consecutive cols
    const int ecol4   = quarter * 64 + lane;        // float4 idx within a dp-row

    const float sigma_v = sigma[0];

    const float4* __restrict__ x4 = reinterpret_cast<const float4*>(x);

    // ---- stage embed (d-pair interleaved) + enorm into LDS (once) ----
#pragma unroll
    for (int i = 0; i < 8; ++i) {
        int idx = tid + i * NTHREADS;          // 0..8191 float4s
        int dp  = idx >> 8;                    // d-pair 0..31
        int c0  = (idx & 255) * 2;             // even col
        float2 a = *reinterpret_cast<const float2*>(&embed[(2 * dp)     * KCODES + c0]);
        float2 b = *reinterpret_cast<const float2*>(&embed[(2 * dp + 1) * KCODES + c0]);
        eP4[idx] = make_float4(a.x, b.x, a.y, b.y);
    }
    if (tid < KCODES) enL[tid] = enorm[tid];

    float likpart[2] = {0.0f, 0.0f};

#pragma unroll 1
    for (int t = 0; t < NTILES; ++t) {
        const int rowtile = blockIdx.x * NTILES + t;
        const int tilerow = rowtile * MTILE;

        // ---- stage x tile (32 rows x 16 f4), coalesced ----
        __syncthreads();   // also covers first-iter embed staging
        if (tid < 512) {
            int row = tid >> 4, d4 = tid & 15;
            xL4[row * XL_STRIDE + d4] = x4[(size_t)(tilerow + row) * 16 + d4];
        }
        __syncthreads();

        float acc[8][2];
#pragma unroll
        for (int r = 0; r < 8; ++r) { acc[r][0] = 0.0f; acc[r][1] = 0.0f; }

        // ---- GEMM: 16 d4-steps, 64 FMA per step ----
#pragma unroll 1
        for (int d4 = 0; d4 < 16; ++d4) {
            // ea: d=4d4,4d4+1 x cols (c0,c1); eb: d=4d4+2,4d4+3
            float4 ea = eP4[(2 * d4)     * 256 + ecol4];
            float4 eb = eP4[(2 * d4 + 1) * 256 + ecol4];
#pragma unroll
            for (int r = 0; r < 8; ++r) {
                float4 xv = xL4[(rgrp * 8 + r) * XL_STRIDE + d4];  // broadcast
                // ascending-d sequential fma chain per (r,col) — bit-exact
                acc[r][0] = fmaf(xv.x, ea.x, acc[r][0]);
                acc[r][1] = fmaf(xv.x, ea.z, acc[r][1]);
                acc[r][0] = fmaf(xv.y, ea.y, acc[r][0]);
                acc[r][1] = fmaf(xv.y, ea.w, acc[r][1]);
                acc[r][0] = fmaf(xv.z, eb.x, acc[r][0]);
                acc[r][1] = fmaf(xv.z, eb.z, acc[r][1]);
                acc[r][0] = fmaf(xv.w, eb.y, acc[r][0]);
                acc[r][1] = fmaf(xv.w, eb.w, acc[r][1]);
            }
        }

        // ---- xnorm for the wave's 8 rows (numpy pairwise-8, from LDS) ----
        const int r_l = lane >> 3;
        const int j_l = lane & 7;
        float xr;
        {
            const float* xp = lds + XL_OFF + (rgrp * 8 + r_l) * 68 + j_l;
            float v0 = xp[0];
            float s = __fmul_rn(v0, v0);
#pragma unroll
            for (int i = 1; i < 8; ++i) {
                float v = xp[8 * i];
                s = __fadd_rn(s, __fmul_rn(v, v));
            }
            float tt;
            tt = __shfl_xor(s, 1, 64); s = __fadd_rn(s, tt);
            tt = __shfl_xor(s, 2, 64); s = __fadd_rn(s, tt);
            tt = __shfl_xor(s, 4, 64); s = __fadd_rn(s, tt);
            xr = s;   // lane r*8+j holds xnorm of wave-local row r
        }

        // enorm for this thread's 2 cols
        float2 env = reinterpret_cast<const float2*>(enL)[quarter * 64 + lane];
        float en[2] = {env.x, env.y};

        // ---- softmax/argmax epilogue, 2 groups of 4 rows ----
#pragma unroll 1
        for (int g = 0; g < 2; ++g) {
            const int base = g * 256;
            float mw4[4];
#pragma unroll
            for (int i = 0; i < 4; ++i) {
                int ri = g * 4 + i;
                float xn = __shfl(xr, ri * 8, 64);
                float mm = -INFINITY;
#pragma unroll
                for (int q = 0; q < 2; ++q) {
                    float dot  = acc[ri][q];
                    float td   = __fsub_rn(xn, __fmul_rn(2.0f, dot));
                    float dist = __fadd_rn(td, en[q]);
                    float zz   = __fmul_rn(-sigma_v, dist);
                    acc[ri][q] = zz;
                    mm = fmaxf(mm, zz);
                }
#pragma unroll
                for (int mask = 1; mask < 64; mask <<= 1)
                    mm = fmaxf(mm, __shfl_xor(mm, mask, 64));
                mw4[i] = mm;
            }
            if (lane < 4)
                scratch[base + (rgrp * 4 + lane) * 4 + quarter] = mw4[lane];
            __syncthreads();
#pragma unroll
            for (int i = 0; i < 4; ++i) {
                int slot = base + (rgrp * 4 + i) * 4;
                float m0 = scratch[slot + 0], m1 = scratch[slot + 1];
                float m2 = scratch[slot + 2], m3 = scratch[slot + 3];
                mw4[i] = fmaxf(fmaxf(m0, m1), fmaxf(m2, m3));
            }

            float sw[4], bv[4]; int bc[4];
#pragma unroll
            for (int i = 0; i < 4; ++i) {
                int ri = g * 4 + i;
                float ssum = 0.0f, best = -1.0f; int bcol = KCODES;
#pragma unroll
                for (int q = 0; q < 2; ++q) {
                    float ee = expf(__fsub_rn(acc[ri][q], mw4[i]));
                    acc[ri][q] = ee;
                    ssum += ee;
                    int col = colb + q;
                    if (ee > best) { best = ee; bcol = col; }
                }
#pragma unroll
                for (int mask = 1; mask < 64; mask <<= 1)
                    ssum += __shfl_xor(ssum, mask, 64);
#pragma unroll
                for (int mask = 1; mask < 64; mask <<= 1) {
                    float ov = __shfl_xor(best, mask, 64);
                    int   oc = __shfl_xor(bcol, mask, 64);
                    if (ov > best || (ov == best && oc < bcol)) { best = ov; bcol = oc; }
                }
                sw[i] = ssum; bv[i] = best; bc[i] = bcol;
            }
            if (lane < 4) {
                int slot = (rgrp * 4 + lane) * 4 + quarter;
                scratch[base +  64 + slot] = sw[lane];
                scratch[base + 128 + slot] = bv[lane];
                scratch[base + 192 + slot] = __int_as_float(bc[lane]);
            }
            __syncthreads();
#pragma unroll
            for (int i = 0; i < 4; ++i) {
                int ri = g * 4 + i;
                int slot = base + (rgrp * 4 + i) * 4;
                // s: fixed quarter order 0,1,2,3 — identical on every wave
                float stot = scratch[slot + 64 + 0];
                stot = __fadd_rn(stot, scratch[slot + 64 + 1]);
                stot = __fadd_rn(stot, scratch[slot + 64 + 2]);
                stot = __fadd_rn(stot, scratch[slot + 64 + 3]);
                // argmax: quarters are ascending col ranges; strict > keeps first
                float best = scratch[slot + 128 + 0];
                int   bcol = __float_as_int(scratch[slot + 192 + 0]);
#pragma unroll
                for (int qq = 1; qq < 4; ++qq) {
                    float ov = scratch[slot + 128 + qq];
                    int   oc = __float_as_int(scratch[slot + 192 + qq]);
                    if (ov > best) { best = ov; bcol = oc; }
                }
                float invS = 1.0f / stot;
#pragma unroll
                for (int q = 0; q < 2; ++q)
                    likpart[q] = fmaf(acc[ri][q], invS, likpart[q]);
                if (quarter == 0) {
                    int row = tilerow + rgrp * 8 + ri;
                    __builtin_nontemporal_store(embedT[bcol * DIMS + lane],
                                                &out[(size_t)row * DIMS + lane]);
                }
            }
            __syncthreads();   // protect scratch region before reuse
        }
    }

    // ---- block-level likelihood reduction (scratch[0..511]) ----
    if (tid < KCODES) scratch[tid] = 0.0f;
    __syncthreads();
    atomicAdd(&scratch[colb + 0], likpart[0]);
    atomicAdd(&scratch[colb + 1], likpart[1]);
    __syncthreads();
    if (tid < KCODES) atomicAdd(&lik[tid], scratch[tid]);
}

// ---------------------------------------------------------------------------
// finish: likelihoods = lik_sum / N; quant_loss = 0.25*mean(p*(log p - log(l+eps)))
// ---------------------------------------------------------------------------
__global__ void finish_kernel(const float* __restrict__ lik,
                              float* __restrict__ out) {
    int tid = threadIdx.x;   // 512 threads
    float l = lik[tid] / 262144.0f;     // exact: divide by 2^18
    out[16777217 + tid] = l;
    const float p = 1.0f / 512.0f;
    float term = __fmul_rn(p, __fsub_rn(logf(p), logf(l + 1e-10f)));
#pragma unroll
    for (int mask = 1; mask < 64; mask <<= 1)
        term += __shfl_xor(term, mask, 64);
    __shared__ float ws[8];
    if ((tid & 63) == 0) ws[tid >> 6] = term;
    __syncthreads();
    if (tid == 0) {
        float ssum = 0.0f;
        for (int i = 0; i < 8; ++i) ssum += ws[i];
        out[16777216] = 0.25f * (ssum / 512.0f);
    }
}

extern "C" void kernel_launch(void* const* d_in, const int* in_sizes, int n_in,
                              void* d_out, int out_size, void* d_ws, size_t ws_size,
                              hipStream_t stream) {
    const float* x     = (const float*)d_in[0];
    const float* embed = (const float*)d_in[1];
    const float* sigma = (const float*)d_in[2];
    float* out = (float*)d_out;
    float* ws  = (float*)d_ws;

    float* embedT = ws;             // 512*64 = 32768 floats
    float* enorm  = ws + 32768;     // 512 floats
    float* lik    = ws + 33280;     // 512 floats

    hipFuncSetAttribute(reinterpret_cast<const void*>(main_kernel),
                        hipFuncAttributeMaxDynamicSharedMemorySize, LDS_BYTES);

    prep_kernel<<<KCODES, DIMS, 0, stream>>>(embed, embedT, enorm, lik);
    main_kernel<<<NBLOCKS, NTHREADS, LDS_BYTES, stream>>>(x, embed, sigma,
                                                          embedT, enorm, lik, out);
    finish_kernel<<<1, NTHREADS, 0, stream>>>(lik, out);
}